// Round 1
// baseline (351.731 us; speedup 1.0000x reference)
//
#include <hip/hip_runtime.h>
#include <hip/hip_bf16.h>
#include <cstdint>

#define DM 1024
#define HEADS 16
#define DH 64
#define SEQ 2048
#define BATCH 2

typedef __attribute__((ext_vector_type(8))) short bf16x8;
typedef __attribute__((ext_vector_type(4))) float f32x4;

static __device__ __forceinline__ unsigned short f2bf(float f) {
    unsigned u = __builtin_bit_cast(unsigned, f);
    u = u + 0x7fffu + ((u >> 16) & 1u);
    return (unsigned short)(u >> 16);
}

// ---------------- cast fp32 -> bf16 (vectorized) ----------------
__global__ void cast_bf16_k(const float* __restrict__ s, unsigned short* __restrict__ d, int n) {
    int i = (blockIdx.x * 256 + threadIdx.x) * 8;
    if (i + 8 <= n) {
        float4 a = *(const float4*)(s + i);
        float4 b = *(const float4*)(s + i + 4);
        ushort4 o0, o1;
        o0.x = f2bf(a.x); o0.y = f2bf(a.y); o0.z = f2bf(a.z); o0.w = f2bf(a.w);
        o1.x = f2bf(b.x); o1.y = f2bf(b.y); o1.z = f2bf(b.z); o1.w = f2bf(b.w);
        *(ushort4*)(d + i) = o0;
        *(ushort4*)(d + i + 4) = o1;
    }
}

// ---------------- NT GEMM: C[m][n] = sum_k A[m][k]*B[n][k] + bias[n] ----------------
// EPI 0: bf16 out row-major [M][N]
// EPI 1: bf16 out transposed per-head: Vt[b][h][d][s]  (n = h*64+d, m = b*2048+s)
// EPI 2: fp32 out row-major [M][N]
template<int EPI>
__global__ __launch_bounds__(256) void gemm_nt(
    const unsigned short* __restrict__ A,
    const unsigned short* __restrict__ Bw,
    const float* __restrict__ bias,
    void* __restrict__ Cout,
    int M, int N, int K)
{
    constexpr int BM = 128, BN = 128, BK = 32;
    __shared__ alignas(16) unsigned short As[BM * BK];
    __shared__ alignas(16) unsigned short Bs[BN * BK];

    const int t = threadIdx.x;
    const int lane = t & 63;
    const int w = t >> 6;
    const int wm = (w >> 1) * 64, wn = (w & 1) * 64;
    const int lr = lane & 15, lg = lane >> 4;
    const int m0 = blockIdx.x * BM, n0 = blockIdx.y * BN;

    f32x4 acc[4][4] = {};

    const int srow = t >> 2;            // staging row within tile (0..63) + c*64
    const int scol = (t & 3) * 8;       // staging col offset in elements (16B chunks)

    for (int kt = 0; kt < K; kt += BK) {
#pragma unroll
        for (int c = 0; c < 2; c++) {
            int row = srow + c * 64;
            __builtin_amdgcn_global_load_lds(
                (const __attribute__((address_space(1))) unsigned int*)(A + (size_t)(m0 + row) * K + kt + scol),
                (__attribute__((address_space(3))) unsigned int*)(&As[row * BK + scol]), 16, 0, 0);
            __builtin_amdgcn_global_load_lds(
                (const __attribute__((address_space(1))) unsigned int*)(Bw + (size_t)(n0 + row) * K + kt + scol),
                (__attribute__((address_space(3))) unsigned int*)(&Bs[row * BK + scol]), 16, 0, 0);
        }
        __syncthreads();

        bf16x8 af[4], bfr[4];
#pragma unroll
        for (int i = 0; i < 4; i++) {
            af[i]  = *(const bf16x8*)(&As[(wm + i * 16 + lr) * BK + lg * 8]);
            bfr[i] = *(const bf16x8*)(&Bs[(wn + i * 16 + lr) * BK + lg * 8]);
        }
#pragma unroll
        for (int i = 0; i < 4; i++)
#pragma unroll
            for (int j = 0; j < 4; j++)
                acc[i][j] = __builtin_amdgcn_mfma_f32_16x16x32_bf16(af[i], bfr[j], acc[i][j], 0, 0, 0);
        __syncthreads();
    }

    // epilogue: frag (i,j): global row = m0+wm+i*16+4*lg+r, col = n0+wn+j*16+lr
    if constexpr (EPI == 0) {
        unsigned short* C = (unsigned short*)Cout;
#pragma unroll
        for (int i = 0; i < 4; i++) {
            int rbase = m0 + wm + i * 16 + lg * 4;
#pragma unroll
            for (int j = 0; j < 4; j++) {
                int col = n0 + wn + j * 16 + lr;
                float bv = bias[col];
#pragma unroll
                for (int r = 0; r < 4; r++)
                    C[(size_t)(rbase + r) * N + col] = f2bf(acc[i][j][r] + bv);
            }
        }
    } else if constexpr (EPI == 1) {
        unsigned short* C = (unsigned short*)Cout;
        int b = m0 >> 11;
#pragma unroll
        for (int i = 0; i < 4; i++) {
            int s0 = (m0 & 2047) + wm + i * 16 + lg * 4;
#pragma unroll
            for (int j = 0; j < 4; j++) {
                int n = n0 + wn + j * 16 + lr;
                float bv = bias[n];
                int h = n >> 6, d = n & 63;
                ushort4 st;
                st.x = f2bf(acc[i][j][0] + bv);
                st.y = f2bf(acc[i][j][1] + bv);
                st.z = f2bf(acc[i][j][2] + bv);
                st.w = f2bf(acc[i][j][3] + bv);
                *(ushort4*)(C + ((size_t)((b * HEADS + h) * DH + d)) * SEQ + s0) = st;
            }
        }
    } else {
        float* C = (float*)Cout;
#pragma unroll
        for (int i = 0; i < 4; i++) {
            int rbase = m0 + wm + i * 16 + lg * 4;
#pragma unroll
            for (int j = 0; j < 4; j++) {
                int col = n0 + wn + j * 16 + lr;
                float bv = bias[col];
#pragma unroll
                for (int r = 0; r < 4; r++)
                    C[(size_t)(rbase + r) * N + col] = acc[i][j][r] + bv;
            }
        }
    }
}

// ---------------- causal flash attention ----------------
// Qp,Kp: bf16 [B][S][H*64] ; Vt: bf16 [B][H][64][S] ; Ctx out: bf16 [B][S][H*64]
// block = 4 waves; wave w handles 16 q rows at q0 = blockIdx.x*64 + w*16 of head (blockIdx.y), batch (blockIdx.z)
__global__ __launch_bounds__(256) void attn_k(
    const unsigned short* __restrict__ Qp,
    const unsigned short* __restrict__ Kp,
    const unsigned short* __restrict__ Vt,
    unsigned short* __restrict__ Ctx)
{
    __shared__ alignas(16) unsigned short p_lds[4][16][72];  // [wave][q][k] padded

    const int lane = threadIdx.x & 63;
    const int wq = threadIdx.x >> 6;
    const int lr = lane & 15, lg = lane >> 4;
    const int b = blockIdx.z, h = blockIdx.y;
    const int q0 = blockIdx.x * 64 + wq * 16;
    const int qpos = q0 + lr;

    // Q fragments (b-operand): lane holds Q[qpos][d], d = dstep*32 + lg*8 .. +7
    bf16x8 qf0, qf1;
    {
        const unsigned short* qb = Qp + (size_t)(b * SEQ + qpos) * DM + h * DH + lg * 8;
        qf0 = *(const bf16x8*)(qb);
        qf1 = *(const bf16x8*)(qb + 32);
    }

    float m_run = -1e30f, l_run = 0.f;
    f32x4 o[4] = {};   // o[dt]: d = dt*16 + 4*lg + r, col q = lr

    const unsigned short* kb_base = Kp + (size_t)(b * SEQ) * DM + h * DH + lg * 8;
    const unsigned short* v_base = Vt + ((size_t)(b * HEADS + h) * DH + lr) * SEQ + lg * 8;

    for (int kb = 0; kb < q0 + 16; kb += 64) {
        // S = K . Q^T : sc[t] rows k_local = t*16 + 4*lg + r, col q = lr
        f32x4 sc[4] = {};
#pragma unroll
        for (int tt = 0; tt < 4; tt++) {
            const unsigned short* kp = kb_base + (size_t)(kb + tt * 16 + lr) * DM;
            bf16x8 k0 = *(const bf16x8*)(kp);
            bf16x8 k1 = *(const bf16x8*)(kp + 32);
            sc[tt] = __builtin_amdgcn_mfma_f32_16x16x32_bf16(k0, qf0, sc[tt], 0, 0, 0);
            sc[tt] = __builtin_amdgcn_mfma_f32_16x16x32_bf16(k1, qf1, sc[tt], 0, 0, 0);
        }
        // scale + causal mask + per-lane partial max (16 scores per lane, all same q)
        float sv[16];
        float mloc = -1e30f;
#pragma unroll
        for (int tt = 0; tt < 4; tt++)
#pragma unroll
            for (int r = 0; r < 4; r++) {
                int kpos = kb + tt * 16 + lg * 4 + r;
                float v = sc[tt][r] * 0.125f;
                v = (kpos <= qpos) ? v : -1e30f;
                sv[tt * 4 + r] = v;
                mloc = fmaxf(mloc, v);
            }
        // reduce across the 4 lane-groups (same lr)
        mloc = fmaxf(mloc, __shfl_xor(mloc, 16));
        mloc = fmaxf(mloc, __shfl_xor(mloc, 32));
        float m_new = fmaxf(m_run, mloc);
        float sf = __expf(m_run - m_new);

        float ps = 0.f;
        ushort4 pw[4];
#pragma unroll
        for (int tt = 0; tt < 4; tt++) {
            float p0 = __expf(sv[tt * 4 + 0] - m_new);
            float p1 = __expf(sv[tt * 4 + 1] - m_new);
            float p2 = __expf(sv[tt * 4 + 2] - m_new);
            float p3 = __expf(sv[tt * 4 + 3] - m_new);
            ps += p0 + p1 + p2 + p3;
            pw[tt].x = f2bf(p0); pw[tt].y = f2bf(p1); pw[tt].z = f2bf(p2); pw[tt].w = f2bf(p3);
        }
        ps += __shfl_xor(ps, 16);
        ps += __shfl_xor(ps, 32);
        l_run = l_run * sf + ps;
        m_run = m_new;
#pragma unroll
        for (int dt = 0; dt < 4; dt++) {
            o[dt][0] *= sf; o[dt][1] *= sf; o[dt][2] *= sf; o[dt][3] *= sf;
        }
        // P to LDS (per-wave region): p_lds[wq][q=lr][k = tt*16 + 4*lg + r]
#pragma unroll
        for (int tt = 0; tt < 4; tt++)
            *(ushort4*)(&p_lds[wq][lr][tt * 16 + lg * 4]) = pw[tt];
        // PV: O^T[d][q] += Vt[d][kv] * P[q][kv]
#pragma unroll
        for (int kv = 0; kv < 2; kv++) {
            bf16x8 pf = *(const bf16x8*)(&p_lds[wq][lr][kv * 32 + lg * 8]);
#pragma unroll
            for (int dt = 0; dt < 4; dt++) {
                bf16x8 vf = *(const bf16x8*)(v_base + (size_t)(dt * 16) * SEQ + kb + kv * 32);
                o[dt] = __builtin_amdgcn_mfma_f32_16x16x32_bf16(vf, pf, o[dt], 0, 0, 0);
            }
        }
    }

    float inv_l = 1.0f / l_run;
    unsigned short* cb = Ctx + (size_t)(b * SEQ + qpos) * DM + h * DH + lg * 4;
#pragma unroll
    for (int dt = 0; dt < 4; dt++) {
        ushort4 st;
        st.x = f2bf(o[dt][0] * inv_l);
        st.y = f2bf(o[dt][1] * inv_l);
        st.z = f2bf(o[dt][2] * inv_l);
        st.w = f2bf(o[dt][3] * inv_l);
        *(ushort4*)(cb + dt * 16) = st;
    }
}

extern "C" void kernel_launch(void* const* d_in, const int* in_sizes, int n_in,
                              void* d_out, int out_size, void* d_ws, size_t ws_size,
                              hipStream_t stream)
{
    const float* query = (const float*)d_in[0];
    const float* keyv  = (const float*)d_in[1];
    const float* Wq = (const float*)d_in[2];
    const float* bq = (const float*)d_in[3];
    const float* Wk = (const float*)d_in[4];
    const float* bk = (const float*)d_in[5];
    const float* Wv = (const float*)d_in[6];
    const float* bv = (const float*)d_in[7];
    const float* Wo = (const float*)d_in[8];
    const float* bo = (const float*)d_in[9];
    float* out = (float*)d_out;

    const int M = BATCH * SEQ;          // 4096
    char* ws = (char*)d_ws;
    size_t off = 0;
    auto alloc = [&](size_t elems) { unsigned short* p = (unsigned short*)(ws + off); off += elems * 2; return p; };
    unsigned short* qb  = alloc((size_t)M * DM);
    unsigned short* kvb = alloc((size_t)M * DM);
    unsigned short* wqb = alloc((size_t)DM * DM);
    unsigned short* wkb = alloc((size_t)DM * DM);
    unsigned short* wvb = alloc((size_t)DM * DM);
    unsigned short* wob = alloc((size_t)DM * DM);
    unsigned short* Qp  = alloc((size_t)M * DM);
    unsigned short* Kp  = alloc((size_t)M * DM);
    unsigned short* Vt  = alloc((size_t)M * DM);
    unsigned short* Ctx = alloc((size_t)M * DM);

    auto cast = [&](const float* s, unsigned short* d, int n) {
        cast_bf16_k<<<n / 2048, 256, 0, stream>>>(s, d, n);
    };
    cast(query, qb, M * DM);
    cast(keyv, kvb, M * DM);
    cast(Wq, wqb, DM * DM);
    cast(Wk, wkb, DM * DM);
    cast(Wv, wvb, DM * DM);
    cast(Wo, wob, DM * DM);

    dim3 g(M / 128, DM / 128), blk(256);
    gemm_nt<0><<<g, blk, 0, stream>>>(qb,  wqb, bq, Qp, M, DM, DM);
    gemm_nt<0><<<g, blk, 0, stream>>>(kvb, wkb, bk, Kp, M, DM, DM);
    gemm_nt<1><<<g, blk, 0, stream>>>(kvb, wvb, bv, Vt, M, DM, DM);

    attn_k<<<dim3(SEQ / 64, HEADS, BATCH), 256, 0, stream>>>(Qp, Kp, Vt, Ctx);

    gemm_nt<2><<<g, blk, 0, stream>>>(Ctx, wob, bo, out, M, DM, DM);
}

// Round 2
// 190.002 us; speedup vs baseline: 1.8512x; 1.8512x over previous
//
#include <hip/hip_runtime.h>
#include <hip/hip_bf16.h>
#include <cstdint>
#include <type_traits>

#define DM 1024
#define HEADS 16
#define DH 64
#define SEQ 2048
#define BATCH 2

typedef __attribute__((ext_vector_type(8))) short bf16x8;
typedef __attribute__((ext_vector_type(4))) float f32x4;
typedef __attribute__((ext_vector_type(16))) float f32x16;
typedef __attribute__((ext_vector_type(2))) unsigned int u32x2;
typedef __attribute__((ext_vector_type(4))) unsigned int u32x4;

static __device__ __forceinline__ unsigned short f2bf(float f) {
    unsigned u = __builtin_bit_cast(unsigned, f);
    u = u + 0x7fffu + ((u >> 16) & 1u);
    return (unsigned short)(u >> 16);
}

// ---------------- cast fp32 -> bf16 (vectorized) ----------------
__global__ void cast_bf16_k(const float* __restrict__ s, unsigned short* __restrict__ d, int n) {
    int i = (blockIdx.x * 256 + threadIdx.x) * 8;
    if (i + 8 <= n) {
        float4 a = *(const float4*)(s + i);
        float4 b = *(const float4*)(s + i + 4);
        ushort4 o0, o1;
        o0.x = f2bf(a.x); o0.y = f2bf(a.y); o0.z = f2bf(a.z); o0.w = f2bf(a.w);
        o1.x = f2bf(b.x); o1.y = f2bf(b.y); o1.z = f2bf(b.z); o1.w = f2bf(b.w);
        *(ushort4*)(d + i) = o0;
        *(ushort4*)(d + i + 4) = o1;
    }
}

// ---------------- NT GEMM: C[m][n] = sum_k A[m][k]*B[n][k] + bias[n] ----------------
template<int EPI>
__global__ __launch_bounds__(256) void gemm_nt(
    const unsigned short* __restrict__ A,
    const unsigned short* __restrict__ Bw,
    const float* __restrict__ bias,
    void* __restrict__ Cout,
    int M, int N, int K)
{
    constexpr int BM = 128, BN = 128, BK = 32;
    __shared__ alignas(16) unsigned short As[BM * BK];
    __shared__ alignas(16) unsigned short Bs[BN * BK];

    const int t = threadIdx.x;
    const int lane = t & 63;
    const int w = t >> 6;
    const int wm = (w >> 1) * 64, wn = (w & 1) * 64;
    const int lr = lane & 15, lg = lane >> 4;
    const int m0 = blockIdx.x * BM, n0 = blockIdx.y * BN;

    f32x4 acc[4][4] = {};

    const int srow = t >> 2;
    const int scol = (t & 3) * 8;

    for (int kt = 0; kt < K; kt += BK) {
#pragma unroll
        for (int c = 0; c < 2; c++) {
            int row = srow + c * 64;
            __builtin_amdgcn_global_load_lds(
                (const __attribute__((address_space(1))) unsigned int*)(A + (size_t)(m0 + row) * K + kt + scol),
                (__attribute__((address_space(3))) unsigned int*)(&As[row * BK + scol]), 16, 0, 0);
            __builtin_amdgcn_global_load_lds(
                (const __attribute__((address_space(1))) unsigned int*)(Bw + (size_t)(n0 + row) * K + kt + scol),
                (__attribute__((address_space(3))) unsigned int*)(&Bs[row * BK + scol]), 16, 0, 0);
        }
        __syncthreads();

        bf16x8 af[4], bfr[4];
#pragma unroll
        for (int i = 0; i < 4; i++) {
            af[i]  = *(const bf16x8*)(&As[(wm + i * 16 + lr) * BK + lg * 8]);
            bfr[i] = *(const bf16x8*)(&Bs[(wn + i * 16 + lr) * BK + lg * 8]);
        }
#pragma unroll
        for (int i = 0; i < 4; i++)
#pragma unroll
            for (int j = 0; j < 4; j++)
                acc[i][j] = __builtin_amdgcn_mfma_f32_16x16x32_bf16(af[i], bfr[j], acc[i][j], 0, 0, 0);
        __syncthreads();
    }

    if constexpr (EPI == 0) {
        unsigned short* C = (unsigned short*)Cout;
#pragma unroll
        for (int i = 0; i < 4; i++) {
            int rbase = m0 + wm + i * 16 + lg * 4;
#pragma unroll
            for (int j = 0; j < 4; j++) {
                int col = n0 + wn + j * 16 + lr;
                float bv = bias[col];
#pragma unroll
                for (int r = 0; r < 4; r++)
                    C[(size_t)(rbase + r) * N + col] = f2bf(acc[i][j][r] + bv);
            }
        }
    } else if constexpr (EPI == 1) {
        unsigned short* C = (unsigned short*)Cout;
        int b = m0 >> 11;
#pragma unroll
        for (int i = 0; i < 4; i++) {
            int s0 = (m0 & 2047) + wm + i * 16 + lg * 4;
#pragma unroll
            for (int j = 0; j < 4; j++) {
                int n = n0 + wn + j * 16 + lr;
                float bv = bias[n];
                int h = n >> 6, d = n & 63;
                ushort4 st;
                st.x = f2bf(acc[i][j][0] + bv);
                st.y = f2bf(acc[i][j][1] + bv);
                st.z = f2bf(acc[i][j][2] + bv);
                st.w = f2bf(acc[i][j][3] + bv);
                *(ushort4*)(C + ((size_t)((b * HEADS + h) * DH + d)) * SEQ + s0) = st;
            }
        }
    } else {
        float* C = (float*)Cout;
#pragma unroll
        for (int i = 0; i < 4; i++) {
            int rbase = m0 + wm + i * 16 + lg * 4;
#pragma unroll
            for (int j = 0; j < 4; j++) {
                int col = n0 + wn + j * 16 + lr;
                float bv = bias[col];
#pragma unroll
                for (int r = 0; r < 4; r++)
                    C[(size_t)(rbase + r) * N + col] = acc[i][j][r] + bv;
            }
        }
    }
}

// ---------------- causal flash attention, 32x32 MFMA, no LDS ----------------
// Qp,Kp: bf16 [B][S][H*64] ; Vt: bf16 [B][H][64][S] ; Ctx: bf16 [B][S][H*64]
// 8 waves/block; wave w -> q-tile (w<4) ? 4j+w : 63-4j-(w&3); SIMD pair (w,w+4)
// totals exactly 65 iterations -> balanced.
__global__ __launch_bounds__(512, 2) void attn_k(
    const unsigned short* __restrict__ Qp,
    const unsigned short* __restrict__ Kp,
    const unsigned short* __restrict__ Vt,
    unsigned short* __restrict__ Ctx)
{
    const int lane = threadIdx.x & 63;
    const int w = threadIdx.x >> 6;
    const int j = blockIdx.x;
    const int h = blockIdx.y, b = blockIdx.z;
    const int qt = (w < 4) ? (j * 4 + w) : (63 - j * 4 - (w & 3));
    const int q0 = qt * 32;
    const int lq = lane & 31;          // q column (also K kv-row / V d-row index)
    const int hi = lane >> 5;          // k-chunk selector
    const int qq = q0 + lq;

    constexpr float SCALE2 = 0.18033688011112042f;   // (1/8) * log2(e)
    constexpr float THR = 11.5f;                     // defer-max threshold (8 nats)

    // Q B-fragments: lane holds Q[qq][dstep*16 + hi*8 .. +7]
    bf16x8 Qf[4];
    {
        const unsigned short* qb = Qp + (size_t)(b * SEQ + qq) * DM + h * DH + hi * 8;
#pragma unroll
        for (int d = 0; d < 4; d++) Qf[d] = *(const bf16x8*)(qb + d * 16);
    }

    // K A-frag base: row kv = kb + lq, col dstep*16 + hi*8
    const unsigned short* kbase = Kp + ((size_t)(b * SEQ + lq)) * DM + h * DH + hi * 8;
    // V^T A-frag base: row d = dt*32 + lq, col kv = kb + s*16 + hi*8
    const unsigned short* vbase = Vt + ((size_t)((b * HEADS + h) * DH) + lq) * SEQ + hi * 8;

    f32x16 o0 = {}, o1 = {};
    float m_run = -1e30f, l_run = 0.f;

    bf16x8 Kc[4], Vc[4];
#pragma unroll
    for (int d = 0; d < 4; d++) Kc[d] = *(const bf16x8*)(kbase + d * 16);
#pragma unroll
    for (int s = 0; s < 2; s++)
#pragma unroll
        for (int dt = 0; dt < 2; dt++)
            Vc[s * 2 + dt] = *(const bf16x8*)(vbase + (size_t)dt * 32 * SEQ + s * 16);

    int kb = 0;
    auto body = [&](auto DIAG, auto PF) {
        constexpr bool diag = DIAG.value;
        constexpr bool pf = PF.value;
        bf16x8 Kn[4], Vn[4];
        if constexpr (pf) {
            const unsigned short* kp = kbase + (size_t)(kb + 32) * DM;
#pragma unroll
            for (int d = 0; d < 4; d++) Kn[d] = *(const bf16x8*)(kp + d * 16);
            const unsigned short* vp = vbase + kb + 32;
#pragma unroll
            for (int s = 0; s < 2; s++)
#pragma unroll
                for (int dt = 0; dt < 2; dt++)
                    Vn[s * 2 + dt] = *(const bf16x8*)(vp + (size_t)dt * 32 * SEQ + s * 16);
        }

        f32x16 sa = {};
#pragma unroll
        for (int d = 0; d < 4; d++)
            sa = __builtin_amdgcn_mfma_f32_32x32x16_bf16(Kc[d], Qf[d], sa, 0, 0, 0);

        float sv[16];
        float mloc = -1e30f;
#pragma unroll
        for (int r = 0; r < 16; r++) {
            float v = sa[r] * SCALE2;
            if constexpr (diag) {
                int kvl = (r & 3) + 8 * (r >> 2) + 4 * hi;
                v = (kvl <= lq) ? v : -1e30f;
            }
            sv[r] = v;
            mloc = fmaxf(mloc, v);
        }
        mloc = fmaxf(mloc, __shfl_xor(mloc, 32));
        if (!__all(mloc - m_run <= THR)) {
            float m_new = fmaxf(m_run, mloc);
            float sf = __builtin_amdgcn_exp2f(m_run - m_new);
            l_run *= sf;
#pragma unroll
            for (int r = 0; r < 16; r++) { o0[r] *= sf; o1[r] *= sf; }
            m_run = m_new;
        }

        float ps = 0.f;
        unsigned c[8];
#pragma unroll
        for (int i = 0; i < 8; i++) {
            float p0 = __builtin_amdgcn_exp2f(sv[2 * i] - m_run);
            float p1 = __builtin_amdgcn_exp2f(sv[2 * i + 1] - m_run);
            ps += p0 + p1;
            unsigned pk;
            asm("v_cvt_pk_bf16_f32 %0, %1, %2" : "=v"(pk) : "v"(p0), "v"(p1));
            c[i] = pk;
        }
        ps += __shfl_xor(ps, 32);
        l_run += ps;

        u32x2 r02 = __builtin_amdgcn_permlane32_swap(c[0], c[2], false, false);
        u32x2 r13 = __builtin_amdgcn_permlane32_swap(c[1], c[3], false, false);
        u32x2 r46 = __builtin_amdgcn_permlane32_swap(c[4], c[6], false, false);
        u32x2 r57 = __builtin_amdgcn_permlane32_swap(c[5], c[7], false, false);
        u32x4 w0 = {r02.x, r13.x, r02.y, r13.y};
        u32x4 w1 = {r46.x, r57.x, r46.y, r57.y};
        bf16x8 Pb0 = __builtin_bit_cast(bf16x8, w0);
        bf16x8 Pb1 = __builtin_bit_cast(bf16x8, w1);

        o0 = __builtin_amdgcn_mfma_f32_32x32x16_bf16(Vc[0], Pb0, o0, 0, 0, 0);
        o1 = __builtin_amdgcn_mfma_f32_32x32x16_bf16(Vc[1], Pb0, o1, 0, 0, 0);
        o0 = __builtin_amdgcn_mfma_f32_32x32x16_bf16(Vc[2], Pb1, o0, 0, 0, 0);
        o1 = __builtin_amdgcn_mfma_f32_32x32x16_bf16(Vc[3], Pb1, o1, 0, 0, 0);

        if constexpr (pf) {
#pragma unroll
            for (int d = 0; d < 4; d++) Kc[d] = Kn[d];
#pragma unroll
            for (int s = 0; s < 4; s++) Vc[s] = Vn[s];
        }
    };

    for (kb = 0; kb < q0; kb += 32)
        body(std::false_type{}, std::true_type{});
    body(std::true_type{}, std::false_type{});

    float inv = 1.0f / l_run;
    unsigned short* cb = Ctx + (size_t)(b * SEQ + qq) * DM + h * DH + hi * 4;
#pragma unroll
    for (int g = 0; g < 4; g++) {
        ushort4 s0, s1;
        s0.x = f2bf(o0[4 * g + 0] * inv); s0.y = f2bf(o0[4 * g + 1] * inv);
        s0.z = f2bf(o0[4 * g + 2] * inv); s0.w = f2bf(o0[4 * g + 3] * inv);
        s1.x = f2bf(o1[4 * g + 0] * inv); s1.y = f2bf(o1[4 * g + 1] * inv);
        s1.z = f2bf(o1[4 * g + 2] * inv); s1.w = f2bf(o1[4 * g + 3] * inv);
        *(ushort4*)(cb + g * 8) = s0;
        *(ushort4*)(cb + 32 + g * 8) = s1;
    }
}

extern "C" void kernel_launch(void* const* d_in, const int* in_sizes, int n_in,
                              void* d_out, int out_size, void* d_ws, size_t ws_size,
                              hipStream_t stream)
{
    const float* query = (const float*)d_in[0];
    const float* keyv  = (const float*)d_in[1];
    const float* Wq = (const float*)d_in[2];
    const float* bq = (const float*)d_in[3];
    const float* Wk = (const float*)d_in[4];
    const float* bk = (const float*)d_in[5];
    const float* Wv = (const float*)d_in[6];
    const float* bv = (const float*)d_in[7];
    const float* Wo = (const float*)d_in[8];
    const float* bo = (const float*)d_in[9];
    float* out = (float*)d_out;

    const int M = BATCH * SEQ;
    char* ws = (char*)d_ws;
    size_t off = 0;
    auto alloc = [&](size_t elems) { unsigned short* p = (unsigned short*)(ws + off); off += elems * 2; return p; };
    unsigned short* qb  = alloc((size_t)M * DM);
    unsigned short* kvb = alloc((size_t)M * DM);
    unsigned short* wqb = alloc((size_t)DM * DM);
    unsigned short* wkb = alloc((size_t)DM * DM);
    unsigned short* wvb = alloc((size_t)DM * DM);
    unsigned short* wob = alloc((size_t)DM * DM);
    unsigned short* Qp  = alloc((size_t)M * DM);
    unsigned short* Kp  = alloc((size_t)M * DM);
    unsigned short* Vt  = alloc((size_t)M * DM);
    unsigned short* Ctx = alloc((size_t)M * DM);

    auto cast = [&](const float* s, unsigned short* d, int n) {
        cast_bf16_k<<<n / 2048, 256, 0, stream>>>(s, d, n);
    };
    cast(query, qb, M * DM);
    cast(keyv, kvb, M * DM);
    cast(Wq, wqb, DM * DM);
    cast(Wk, wkb, DM * DM);
    cast(Wv, wvb, DM * DM);
    cast(Wo, wob, DM * DM);

    dim3 g(M / 128, DM / 128), blk(256);
    gemm_nt<0><<<g, blk, 0, stream>>>(qb,  wqb, bq, Qp, M, DM, DM);
    gemm_nt<0><<<g, blk, 0, stream>>>(kvb, wkb, bk, Kp, M, DM, DM);
    gemm_nt<1><<<g, blk, 0, stream>>>(kvb, wvb, bv, Vt, M, DM, DM);

    attn_k<<<dim3(8, HEADS, BATCH), 512, 0, stream>>>(Qp, Kp, Vt, Ctx);

    gemm_nt<2><<<g, blk, 0, stream>>>(Ctx, wob, bo, out, M, DM, DM);
}

// Round 3
// 139.174 us; speedup vs baseline: 2.5273x; 1.3652x over previous
//
#include <hip/hip_runtime.h>
#include <hip/hip_bf16.h>
#include <cstdint>

#define DM 1024
#define HEADS 16
#define DH 64
#define SEQ 2048
#define BATCH 2

typedef __attribute__((ext_vector_type(8))) short bf16x8;
typedef __attribute__((ext_vector_type(4))) float f32x4;
typedef __attribute__((ext_vector_type(16))) float f32x16;
typedef __attribute__((ext_vector_type(2))) unsigned int u32x2;
typedef __attribute__((ext_vector_type(4))) unsigned int u32x4;

#define SCALE2 0.18033688011112042f   /* (1/8)*log2(e) */

static __device__ __forceinline__ unsigned short f2bf(float f) {
    unsigned u = __builtin_bit_cast(unsigned, f);
    u = u + 0x7fffu + ((u >> 16) & 1u);
    return (unsigned short)(u >> 16);
}

// ---------------- fused cast fp32 -> bf16, all 6 tensors in one launch ----------------
// segments (in 2048-elem blocks): q:2048, kv:2048, wq/wk/wv/wo:512 each  => 6144 blocks
__global__ __launch_bounds__(256) void cast_all_k(
    const float* __restrict__ q, const float* __restrict__ kv,
    const float* __restrict__ wq, const float* __restrict__ wk,
    const float* __restrict__ wv, const float* __restrict__ wo,
    unsigned short* __restrict__ qb, unsigned short* __restrict__ kvb,
    unsigned short* __restrict__ wqb, unsigned short* __restrict__ wkb,
    unsigned short* __restrict__ wvb, unsigned short* __restrict__ wob)
{
    int blk = blockIdx.x;
    const float* s; unsigned short* d; int base;
    if (blk < 2048)      { s = q;  d = qb;  base = 0; }
    else if (blk < 4096) { s = kv; d = kvb; base = 2048; }
    else if (blk < 4608) { s = wq; d = wqb; base = 4096; }
    else if (blk < 5120) { s = wk; d = wkb; base = 4608; }
    else if (blk < 5632) { s = wv; d = wvb; base = 5120; }
    else                 { s = wo; d = wob; base = 5632; }
    int i = ((blk - base) * 256 + threadIdx.x) * 8;
    float4 a = *(const float4*)(s + i);
    float4 b2 = *(const float4*)(s + i + 4);
    ushort4 o0, o1;
    o0.x = f2bf(a.x);  o0.y = f2bf(a.y);  o0.z = f2bf(a.z);  o0.w = f2bf(a.w);
    o1.x = f2bf(b2.x); o1.y = f2bf(b2.y); o1.z = f2bf(b2.z); o1.w = f2bf(b2.w);
    *(ushort4*)(d + i) = o0;
    *(ushort4*)(d + i + 4) = o1;
}

// ---------------- NT GEMM: C[m][n] = sum_k A[m][k]*B[n][k] + bias[n] ----------------
// BM=64 BN=128 BK=64, 4 waves, T2 XOR-swizzled LDS (pre-swizzled global source).
// EPI 0: Q proj  -> bf16 row-major [M][1024], scaled by SCALE2
// EPI 1: merged KV (N=2048): n<1024 -> Kp bf16 row-major; n>=1024 -> Vt[b][h][d][s]
// EPI 2: O proj  -> f32 row-major [M][1024]
template<int EPI>
__global__ __launch_bounds__(256) void gemm_nt(
    const unsigned short* __restrict__ A,
    const unsigned short* __restrict__ Bw,
    const float* __restrict__ biasA,
    const float* __restrict__ biasB,
    void* __restrict__ out0,
    void* __restrict__ out1,
    int M, int N, int K)
{
    constexpr int BK = 64;
    __shared__ alignas(16) unsigned short As[64 * BK];
    __shared__ alignas(16) unsigned short Bs[128 * BK];

    const int t = threadIdx.x;
    const int lane = t & 63;
    const int w = t >> 6;
    const int wn = w * 32;
    const int lr = lane & 15, lg = lane >> 4;
    const int m0 = blockIdx.x * 64, n0 = blockIdx.y * 128;

    f32x4 acc[4][2] = {};

    const int srow = t >> 3;       // 0..31
    const int schunk = t & 7;      // 16B chunk within a 128B row

    for (int kt = 0; kt < K; kt += BK) {
#pragma unroll
        for (int c = 0; c < 2; c++) {
            int row = srow + c * 32;
            int gc = schunk ^ (row & 7);
            __builtin_amdgcn_global_load_lds(
                (const __attribute__((address_space(1))) unsigned int*)(A + (size_t)(m0 + row) * K + kt + gc * 8),
                (__attribute__((address_space(3))) unsigned int*)(&As[row * BK + schunk * 8]), 16, 0, 0);
        }
#pragma unroll
        for (int c = 0; c < 4; c++) {
            int row = srow + c * 32;
            int gc = schunk ^ (row & 7);
            __builtin_amdgcn_global_load_lds(
                (const __attribute__((address_space(1))) unsigned int*)(Bw + (size_t)(n0 + row) * K + kt + gc * 8),
                (__attribute__((address_space(3))) unsigned int*)(&Bs[row * BK + schunk * 8]), 16, 0, 0);
        }
        __syncthreads();
#pragma unroll
        for (int kk = 0; kk < 2; kk++) {
            bf16x8 af[4], bfr[2];
#pragma unroll
            for (int i = 0; i < 4; i++)
                af[i] = *(const bf16x8*)(&As[(i * 16 + lr) * BK + (((kk * 4 + lg) ^ (lr & 7))) * 8]);
#pragma unroll
            for (int jj = 0; jj < 2; jj++)
                bfr[jj] = *(const bf16x8*)(&Bs[(wn + jj * 16 + lr) * BK + (((kk * 4 + lg) ^ (lr & 7))) * 8]);
#pragma unroll
            for (int i = 0; i < 4; i++)
#pragma unroll
                for (int jj = 0; jj < 2; jj++)
                    acc[i][jj] = __builtin_amdgcn_mfma_f32_16x16x32_bf16(af[i], bfr[jj], acc[i][jj], 0, 0, 0);
        }
        __syncthreads();
    }

    if constexpr (EPI == 0) {
        unsigned short* C = (unsigned short*)out0;
#pragma unroll
        for (int i = 0; i < 4; i++) {
            int rbase = m0 + i * 16 + lg * 4;
#pragma unroll
            for (int jj = 0; jj < 2; jj++) {
                int col = n0 + wn + jj * 16 + lr;
                float bv = biasA[col];
#pragma unroll
                for (int r = 0; r < 4; r++)
                    C[(size_t)(rbase + r) * 1024 + col] = f2bf((acc[i][jj][r] + bv) * SCALE2);
            }
        }
    } else if constexpr (EPI == 1) {
        if (n0 < 1024) {
            unsigned short* C = (unsigned short*)out0;   // Kp row-major
#pragma unroll
            for (int i = 0; i < 4; i++) {
                int rbase = m0 + i * 16 + lg * 4;
#pragma unroll
                for (int jj = 0; jj < 2; jj++) {
                    int col = n0 + wn + jj * 16 + lr;
                    float bv = biasA[col];
#pragma unroll
                    for (int r = 0; r < 4; r++)
                        C[(size_t)(rbase + r) * 1024 + col] = f2bf(acc[i][jj][r] + bv);
                }
            }
        } else {
            unsigned short* C = (unsigned short*)out1;   // Vt[b][h][d][s]
            int bidx = m0 >> 11;
#pragma unroll
            for (int i = 0; i < 4; i++) {
                int s0 = (m0 & 2047) + i * 16 + lg * 4;
#pragma unroll
                for (int jj = 0; jj < 2; jj++) {
                    int nv = n0 - 1024 + wn + jj * 16 + lr;
                    float bv = biasB[nv];
                    int hh = nv >> 6, dd = nv & 63;
                    ushort4 st;
                    st.x = f2bf(acc[i][jj][0] + bv);
                    st.y = f2bf(acc[i][jj][1] + bv);
                    st.z = f2bf(acc[i][jj][2] + bv);
                    st.w = f2bf(acc[i][jj][3] + bv);
                    *(ushort4*)(C + ((size_t)((bidx * HEADS + hh) * DH + dd)) * SEQ + s0) = st;
                }
            }
        }
    } else {
        float* C = (float*)out0;
#pragma unroll
        for (int i = 0; i < 4; i++) {
            int rbase = m0 + i * 16 + lg * 4;
#pragma unroll
            for (int jj = 0; jj < 2; jj++) {
                int col = n0 + wn + jj * 16 + lr;
                float bv = biasA[col];
#pragma unroll
                for (int r = 0; r < 4; r++)
                    C[(size_t)(rbase + r) * 1024 + col] = acc[i][jj][r] + bv;
            }
        }
    }
}

// ---------------- causal flash attention, 2 concurrent KV chains per wave ----------------
// Qp (pre-scaled by SCALE2), Kp: bf16 [B][S][H*64]; Vt: bf16 [B][H][64][S]; Ctx: bf16 [B][S][H*64]
__global__ __launch_bounds__(512, 2) void attn_k(
    const unsigned short* __restrict__ Qp,
    const unsigned short* __restrict__ Kp,
    const unsigned short* __restrict__ Vt,
    unsigned short* __restrict__ Ctx)
{
    const int lane = threadIdx.x & 63;
    const int w = threadIdx.x >> 6;
    const int j = blockIdx.x;
    const int h = blockIdx.y, b = blockIdx.z;
    const int qt = (w < 4) ? (j * 4 + w) : (63 - j * 4 - (w & 3));
    const int q0 = qt * 32;
    const int lq = lane & 31;
    const int hi = lane >> 5;
    const int qq = q0 + lq;
    constexpr float THR = 11.5f;

    bf16x8 Qf[4];
    {
        const unsigned short* qb = Qp + (size_t)(b * SEQ + qq) * DM + h * DH + hi * 8;
#pragma unroll
        for (int d = 0; d < 4; d++) Qf[d] = *(const bf16x8*)(qb + d * 16);
    }

    const unsigned short* kbase = Kp + ((size_t)(b * SEQ + lq)) * DM + h * DH + hi * 8;
    const unsigned short* vbase = Vt + ((size_t)((b * HEADS + h) * DH) + lq) * SEQ + hi * 8;

    const int nt = qt + 1;
    const int nA = nt >> 1;        // chain A: tiles [0, nA)
    const int nB = nt - nA;        // chain B: tiles [nA, nt)   (nB >= nA, holds diagonal)

    f32x16 oA0 = {}, oA1 = {}, oB0 = {}, oB1 = {};
    float mA = -1e30f, lA = 0.f, mB = -1e30f, lB = 0.f;
    bf16x8 KA[4], VA[4], KB[4], VB[4];

    const int qmh0 = qq - 4 * hi;   // causal compare base

    auto loadKV = [&](bf16x8 (&Kc)[4], bf16x8 (&Vc)[4], int kb) {
        const unsigned short* kp = kbase + (size_t)kb * DM;
#pragma unroll
        for (int d = 0; d < 4; d++) Kc[d] = *(const bf16x8*)(kp + d * 16);
        const unsigned short* vp = vbase + kb;
#pragma unroll
        for (int s = 0; s < 2; s++)
#pragma unroll
            for (int dt = 0; dt < 2; dt++)
                Vc[s * 2 + dt] = *(const bf16x8*)(vp + (size_t)dt * 32 * SEQ + s * 16);
    };

    if (nA > 0) loadKV(KA, VA, 0);
    loadKV(KB, VB, nA * 32);

    auto step = [&](bf16x8 (&Kc)[4], bf16x8 (&Vc)[4], f32x16& o0, f32x16& o1,
                    float& m_run, float& l_run, int kb, bool pf) {
        bf16x8 Kn[4], Vn[4];
        if (pf) {
            const unsigned short* kp = kbase + (size_t)(kb + 32) * DM;
#pragma unroll
            for (int d = 0; d < 4; d++) Kn[d] = *(const bf16x8*)(kp + d * 16);
            const unsigned short* vp = vbase + kb + 32;
#pragma unroll
            for (int s = 0; s < 2; s++)
#pragma unroll
                for (int dt = 0; dt < 2; dt++)
                    Vn[s * 2 + dt] = *(const bf16x8*)(vp + (size_t)dt * 32 * SEQ + s * 16);
        }

        f32x16 sa = {};
#pragma unroll
        for (int d = 0; d < 4; d++)
            sa = __builtin_amdgcn_mfma_f32_32x32x16_bf16(Kc[d], Qf[d], sa, 0, 0, 0);

        // branchless causal mask: kv pos = kb + (r&3) + 8*(r>>2) + 4*hi  <= qq
        const int qmh = qmh0 - kb;
#pragma unroll
        for (int r = 0; r < 16; r++) {
            int kvl = (r & 3) + 8 * (r >> 2);
            sa[r] = (kvl <= qmh) ? sa[r] : -1e30f;
        }
        // tree max
        float mx[8];
#pragma unroll
        for (int r = 0; r < 8; r++) mx[r] = fmaxf(sa[2 * r], sa[2 * r + 1]);
#pragma unroll
        for (int r = 0; r < 4; r++) mx[r] = fmaxf(mx[r], mx[r + 4]);
        mx[0] = fmaxf(mx[0], mx[2]);
        mx[1] = fmaxf(mx[1], mx[3]);
        float mloc = fmaxf(mx[0], mx[1]);
        mloc = fmaxf(mloc, __shfl_xor(mloc, 32));

        if (!__all(mloc - m_run <= THR)) {
            float m_new = fmaxf(m_run, mloc);
            float sf = __builtin_amdgcn_exp2f(m_run - m_new);
            l_run *= sf;
#pragma unroll
            for (int r = 0; r < 16; r++) { o0[r] *= sf; o1[r] *= sf; }
            m_run = m_new;
        }

        float ps = 0.f;
        unsigned c[8];
#pragma unroll
        for (int i = 0; i < 8; i++) {
            float p0 = __builtin_amdgcn_exp2f(sa[2 * i] - m_run);
            float p1 = __builtin_amdgcn_exp2f(sa[2 * i + 1] - m_run);
            ps += p0 + p1;
            unsigned pk;
            asm("v_cvt_pk_bf16_f32 %0, %1, %2" : "=v"(pk) : "v"(p0), "v"(p1));
            c[i] = pk;
        }
        ps += __shfl_xor(ps, 32);
        l_run += ps;

        u32x2 r02 = __builtin_amdgcn_permlane32_swap(c[0], c[2], false, false);
        u32x2 r13 = __builtin_amdgcn_permlane32_swap(c[1], c[3], false, false);
        u32x2 r46 = __builtin_amdgcn_permlane32_swap(c[4], c[6], false, false);
        u32x2 r57 = __builtin_amdgcn_permlane32_swap(c[5], c[7], false, false);
        u32x4 w0 = {r02.x, r13.x, r02.y, r13.y};
        u32x4 w1 = {r46.x, r57.x, r46.y, r57.y};
        bf16x8 Pb0 = __builtin_bit_cast(bf16x8, w0);
        bf16x8 Pb1 = __builtin_bit_cast(bf16x8, w1);

        o0 = __builtin_amdgcn_mfma_f32_32x32x16_bf16(Vc[0], Pb0, o0, 0, 0, 0);
        o1 = __builtin_amdgcn_mfma_f32_32x32x16_bf16(Vc[1], Pb0, o1, 0, 0, 0);
        o0 = __builtin_amdgcn_mfma_f32_32x32x16_bf16(Vc[2], Pb1, o0, 0, 0, 0);
        o1 = __builtin_amdgcn_mfma_f32_32x32x16_bf16(Vc[3], Pb1, o1, 0, 0, 0);

        if (pf) {
#pragma unroll
            for (int d = 0; d < 4; d++) Kc[d] = Kn[d];
#pragma unroll
            for (int s = 0; s < 4; s++) Vc[s] = Vn[s];
        }
    };

    for (int i = 0; i < nA; i++) {
        step(KA, VA, oA0, oA1, mA, lA, i * 32, i + 1 < nA);
        step(KB, VB, oB0, oB1, mB, lB, (nA + i) * 32, i + 1 < nB);
    }
    if (nB > nA)
        step(KB, VB, oB0, oB1, mB, lB, (nt - 1) * 32, false);

    // combine chains
    float m = fmaxf(mA, mB);
    float cA = __builtin_amdgcn_exp2f(mA - m);
    float cB = __builtin_amdgcn_exp2f(mB - m);
    float l = lA * cA + lB * cB;
    float inv = 1.0f / l;
    float fA = cA * inv, fB = cB * inv;

    unsigned short* cb = Ctx + (size_t)(b * SEQ + qq) * DM + h * DH + hi * 4;
#pragma unroll
    for (int g = 0; g < 4; g++) {
        ushort4 s0, s1;
        s0.x = f2bf(oA0[4 * g + 0] * fA + oB0[4 * g + 0] * fB);
        s0.y = f2bf(oA0[4 * g + 1] * fA + oB0[4 * g + 1] * fB);
        s0.z = f2bf(oA0[4 * g + 2] * fA + oB0[4 * g + 2] * fB);
        s0.w = f2bf(oA0[4 * g + 3] * fA + oB0[4 * g + 3] * fB);
        s1.x = f2bf(oA1[4 * g + 0] * fA + oB1[4 * g + 0] * fB);
        s1.y = f2bf(oA1[4 * g + 1] * fA + oB1[4 * g + 1] * fB);
        s1.z = f2bf(oA1[4 * g + 2] * fA + oB1[4 * g + 2] * fB);
        s1.w = f2bf(oA1[4 * g + 3] * fA + oB1[4 * g + 3] * fB);
        *(ushort4*)(cb + g * 8) = s0;
        *(ushort4*)(cb + 32 + g * 8) = s1;
    }
}

extern "C" void kernel_launch(void* const* d_in, const int* in_sizes, int n_in,
                              void* d_out, int out_size, void* d_ws, size_t ws_size,
                              hipStream_t stream)
{
    const float* query = (const float*)d_in[0];
    const float* keyv  = (const float*)d_in[1];
    const float* Wq = (const float*)d_in[2];
    const float* bq = (const float*)d_in[3];
    const float* Wk = (const float*)d_in[4];
    const float* bk = (const float*)d_in[5];
    const float* Wv = (const float*)d_in[6];
    const float* bv = (const float*)d_in[7];
    const float* Wo = (const float*)d_in[8];
    const float* bo = (const float*)d_in[9];
    float* out = (float*)d_out;

    const int M = BATCH * SEQ;
    char* ws = (char*)d_ws;
    size_t off = 0;
    auto alloc = [&](size_t elems) { unsigned short* p = (unsigned short*)(ws + off); off += elems * 2; return p; };
    unsigned short* qb  = alloc((size_t)M * DM);
    unsigned short* kvb = alloc((size_t)M * DM);
    unsigned short* wqb = alloc((size_t)DM * DM);
    unsigned short* wkb = alloc((size_t)DM * DM);   // wkb and wvb MUST stay adjacent (merged KV weights)
    unsigned short* wvb = alloc((size_t)DM * DM);
    unsigned short* wob = alloc((size_t)DM * DM);
    unsigned short* Qp  = alloc((size_t)M * DM);
    unsigned short* Kp  = alloc((size_t)M * DM);
    unsigned short* Vt  = alloc((size_t)M * DM);
    unsigned short* Ctx = alloc((size_t)M * DM);

    cast_all_k<<<6144, 256, 0, stream>>>(query, keyv, Wq, Wk, Wv, Wo,
                                         qb, kvb, wqb, wkb, wvb, wob);

    gemm_nt<0><<<dim3(M / 64, 8),  256, 0, stream>>>(qb,  wqb, bq, nullptr, Qp, nullptr, M, DM, DM);
    gemm_nt<1><<<dim3(M / 64, 16), 256, 0, stream>>>(kvb, wkb, bk, bv,      Kp, Vt,      M, 2 * DM, DM);

    attn_k<<<dim3(8, HEADS, BATCH), 512, 0, stream>>>(Qp, Kp, Vt, Ctx);

    gemm_nt<2><<<dim3(M / 64, 8),  256, 0, stream>>>(Ctx, wob, bo, nullptr, out, nullptr, M, DM, DM);
}